// Round 2
// baseline (679.270 us; speedup 1.0000x reference)
//
#include <hip/hip_runtime.h>

#define DFEAT 64

typedef __attribute__((ext_vector_type(8))) short bf16x8;   // 8 bf16 = 4 VGPRs
typedef __attribute__((ext_vector_type(4))) float f32x4;

// ---------------- bf16 helpers (OCP bfloat16, RNE pack) ----------------
__device__ __forceinline__ float bfhi(unsigned int u) {   // high 16 bits as bf16
    return __builtin_bit_cast(float, u & 0xFFFF0000u);
}
__device__ __forceinline__ float bflo(unsigned int u) {   // low 16 bits as bf16
    return __builtin_bit_cast(float, u << 16);
}
__device__ __forceinline__ unsigned short f2bf(float f) { // RNE
    unsigned int u = __builtin_bit_cast(unsigned int, f);
    u += 0x7FFFu + ((u >> 16) & 1u);
    return (unsigned short)(u >> 16);
}
__device__ __forceinline__ float4 upk4(uint2 v) {         // 4 bf16 -> 4 fp32
    float4 r;
    r.x = bflo(v.x); r.y = bfhi(v.x);
    r.z = bflo(v.y); r.w = bfhi(v.y);
    return r;
}

// ============================================================================
// fp32 -> bf16 conversion of the input features (once per call)
// ============================================================================
__global__ void __launch_bounds__(256)
cvt_bf16_kernel(const float* __restrict__ in, unsigned short* __restrict__ outb,
                int n4) {   // n4 = total elements / 4
    int i = blockIdx.x * 256 + threadIdx.x;
    if (i >= n4) return;
    const float4 v = reinterpret_cast<const float4*>(in)[i];
    uint2 p;
    p.x = (unsigned int)f2bf(v.x) | ((unsigned int)f2bf(v.y) << 16);
    p.y = (unsigned int)f2bf(v.z) | ((unsigned int)f2bf(v.w) << 16);
    reinterpret_cast<uint2*>(outb)[i] = p;
}

// ============================================================================
// CSR build, binned two-pass.
// Bucket b = 256 consecutive dst nodes. NB = ceil(N/256) <= 512 (N=100000).
// Edges pack into u32: (dst & 255) << 24 | src   (needs src < 2^24).
// ============================================================================

__global__ void __launch_bounds__(256)
bucket_hist_kernel(const int* __restrict__ dsts, int* __restrict__ bhist, int E) {
    __shared__ int h[512];
    const int tid = threadIdx.x;
    h[tid] = 0; h[tid + 256] = 0;
    __syncthreads();
    for (int e = blockIdx.x * 256 + tid; e < E; e += gridDim.x * 256)
        atomicAdd(&h[dsts[e] >> 8], 1);
    __syncthreads();
    for (int b = tid; b < 512; b += 256)
        if (h[b]) atomicAdd(&bhist[b], h[b]);
}

__global__ void __launch_bounds__(256)
bucket_scan_kernel(const int* __restrict__ bhist, int* __restrict__ bbase,
                   int* __restrict__ bcur) {
    __shared__ int sm[512];
    const int tid = threadIdx.x;
    sm[tid] = bhist[tid]; sm[tid + 256] = bhist[tid + 256];
    __syncthreads();
    for (int s = 1; s < 512; s <<= 1) {
        int a0 = (tid >= s) ? sm[tid - s] : 0;
        int a1 = sm[tid + 256 - s];
        __syncthreads();
        sm[tid] += a0; sm[tid + 256] += a1;
        __syncthreads();
    }
    for (int b = tid; b < 512; b += 256) {
        int excl = b ? sm[b - 1] : 0;
        bbase[b] = excl; bcur[b] = excl;
    }
    if (tid == 0) bbase[512] = sm[511];
}

#define BIN_CH 2048
__global__ void __launch_bounds__(256)
bin_kernel(const int* __restrict__ srcs, const int* __restrict__ dsts,
           int* __restrict__ bcur, unsigned int* __restrict__ pairbuf, int E) {
    __shared__ int hist[512];
    __shared__ int sscan[512];
    __shared__ int gbase[512];
    __shared__ unsigned int staged[BIN_CH];
    __shared__ unsigned short sbkt[BIN_CH];

    const int tid = threadIdx.x;
    const int base = blockIdx.x * BIN_CH;
    const int chcnt = min(BIN_CH, E - base);

    hist[tid] = 0; hist[tid + 256] = 0;
    __syncthreads();

    unsigned int pk[8];
    unsigned short bb[8], rr[8];
#pragma unroll
    for (int k = 0; k < 8; ++k) {
        int i = k * 256 + tid;
        if (i < chcnt) {
            int e = base + i;
            int d = dsts[e];
            int s = srcs[e];
            int b = d >> 8;
            int r = atomicAdd(&hist[b], 1);
            pk[k] = ((unsigned int)(d & 255) << 24) | (unsigned int)s;
            bb[k] = (unsigned short)b;
            rr[k] = (unsigned short)r;
        } else {
            bb[k] = 0xFFFFu;
        }
    }
    __syncthreads();

    sscan[tid] = hist[tid]; sscan[tid + 256] = hist[tid + 256];
    __syncthreads();
    for (int s = 1; s < 512; s <<= 1) {
        int a0 = (tid >= s) ? sscan[tid - s] : 0;
        int a1 = sscan[tid + 256 - s];
        __syncthreads();
        sscan[tid] += a0; sscan[tid + 256] += a1;
        __syncthreads();
    }

    for (int b = tid; b < 512; b += 256) {
        int c = hist[b];
        gbase[b] = c ? atomicAdd(&bcur[b], c) : 0;
    }
    __syncthreads();

#pragma unroll
    for (int k = 0; k < 8; ++k) {
        if (bb[k] != 0xFFFFu) {
            int b = bb[k];
            int lpos = (b ? sscan[b - 1] : 0) + rr[k];
            staged[lpos] = pk[k];
            sbkt[lpos] = (unsigned short)b;
        }
    }
    __syncthreads();

    for (int i = tid; i < chcnt; i += 256) {
        int b = sbkt[i];
        int excl = b ? sscan[b - 1] : 0;
        pairbuf[gbase[b] + (i - excl)] = staged[i];
    }
}

__global__ void __launch_bounds__(256)
bucket_fill_kernel(const unsigned int* __restrict__ pairbuf,
                   const int* __restrict__ bbase,
                   int* __restrict__ rowptr, int* __restrict__ col,
                   int N, int E) {
    __shared__ int hist[256];
    __shared__ int scan_[256];
    __shared__ int cur[256];

    const int tid = threadIdx.x;
    const int b = blockIdx.x;
    const int node0 = b << 8;
    const int bb0 = bbase[b];
    const int cnt = bbase[b + 1] - bb0;

    hist[tid] = 0;
    __syncthreads();
    for (int i = tid; i < cnt; i += 256)
        atomicAdd(&hist[pairbuf[bb0 + i] >> 24], 1);
    __syncthreads();

    scan_[tid] = hist[tid];
    __syncthreads();
    for (int s = 1; s < 256; s <<= 1) {
        int a = (tid >= s) ? scan_[tid - s] : 0;
        __syncthreads();
        scan_[tid] += a;
        __syncthreads();
    }
    int excl = tid ? scan_[tid - 1] : 0;
    if (node0 + tid < N) rowptr[node0 + tid] = bb0 + excl;
    if (b == 0 && tid == 0) rowptr[N] = E;
    cur[tid] = bb0 + excl;
    __syncthreads();

    for (int i = tid; i < cnt; i += 256) {
        unsigned int p = pairbuf[bb0 + i];
        int pos = atomicAdd(&cur[p >> 24], 1);
        col[pos] = (int)(p & 0xFFFFFFu);
    }
}

// ============================================================================
// Gather-mean over bf16 feature rows (128 B each). One wave per node.
// ============================================================================
__global__ void __launch_bounds__(256)
gather_mean_kernel(const unsigned short* __restrict__ xb,
                   const int* __restrict__ rowptr, const int* __restrict__ col,
                   unsigned short* __restrict__ meanb, int N) {
    int w = (blockIdx.x * 256 + threadIdx.x) >> 6;
    if (w >= N) return;
    const int lane = threadIdx.x & 63;
    const int r = lane >> 4;
    const int c = lane & 15;
    const uint2* x2 = reinterpret_cast<const uint2*>(xb);
    uint2* mean2 = reinterpret_cast<uint2*>(meanb);

    int st = rowptr[w], en = rowptr[w + 1];
    int deg = en - st;

    if (deg == 0) {
        if (r == 0) mean2[(size_t)w * 16 + c] = make_uint2(0, 0);
        return;
    }

    int nb = col[st + min(lane, deg - 1)];
    float4 acc = make_float4(0, 0, 0, 0);

#pragma unroll
    for (int k = 0; k < 4; ++k) {            // slots 0..15 (always)
        int i = 4 * k + r;
        int q = __shfl(nb, min(i, deg - 1), 64);
        float4 v = upk4(x2[(size_t)q * 16 + c]);
        float m = (i < deg) ? 1.0f : 0.0f;
        acc.x += v.x * m; acc.y += v.y * m; acc.z += v.z * m; acc.w += v.w * m;
    }
    if (deg > 16) {                          // slots 16..31
#pragma unroll
        for (int k = 4; k < 8; ++k) {
            int i = 4 * k + r;
            int q = __shfl(nb, min(i, deg - 1), 64);
            float4 v = upk4(x2[(size_t)q * 16 + c]);
            float m = (i < deg) ? 1.0f : 0.0f;
            acc.x += v.x * m; acc.y += v.y * m; acc.z += v.z * m; acc.w += v.w * m;
        }
    }
    if (deg > 32) {                          // slots 32..63 (rare)
#pragma unroll
        for (int k = 8; k < 16; ++k) {
            int i = 4 * k + r;
            int q = __shfl(nb, min(i, deg - 1), 64);
            float4 v = upk4(x2[(size_t)q * 16 + c]);
            float m = (i < deg) ? 1.0f : 0.0f;
            acc.x += v.x * m; acc.y += v.y * m; acc.z += v.z * m; acc.w += v.w * m;
        }
    }
    for (int base = 64; base < deg; base += 64) {   // ultra-rare tail
        int cnt = deg - base;
        int nb2 = col[st + base + min(lane, cnt - 1)];
#pragma unroll
        for (int k = 0; k < 16; ++k) {
            int i = 4 * k + r;
            int q = __shfl(nb2, min(i, cnt - 1), 64);
            float4 v = upk4(x2[(size_t)q * 16 + c]);
            float m = (i < cnt) ? 1.0f : 0.0f;
            acc.x += v.x * m; acc.y += v.y * m; acc.z += v.z * m; acc.w += v.w * m;
        }
    }

#pragma unroll
    for (int off = 16; off <= 32; off <<= 1) {
        acc.x += __shfl_xor(acc.x, off, 64);
        acc.y += __shfl_xor(acc.y, off, 64);
        acc.z += __shfl_xor(acc.z, off, 64);
        acc.w += __shfl_xor(acc.w, off, 64);
    }
    float inv = 1.0f / (float)deg;
    if (r == 0) {
        uint2 p;
        p.x = (unsigned int)f2bf(acc.x * inv) | ((unsigned int)f2bf(acc.y * inv) << 16);
        p.y = (unsigned int)f2bf(acc.z * inv) | ((unsigned int)f2bf(acc.w * inv) << 16);
        mean2[(size_t)w * 16 + c] = p;
    }
}

// ============================================================================
// MFMA transform: out = [mean|x] @ [Wl|Wr]^T + bl; L2norm; ReLU.
// One wave per 16-node tile, no LDS, no barriers. Weights (fp32, 32KB,
// L2-resident) are converted to bf16 B-fragments in registers once per wave.
// mfma_f32_16x16x32_bf16: A row=lane&15 (node), k=(lane>>4)*8+j;
//                         B col=lane&15 (feat), k=(lane>>4)*8+j;
//                         C/D col=lane&15 (feat), row=(lane>>4)*4+reg (node).
// ============================================================================
__global__ void __launch_bounds__(256)
transform_mfma_kernel(const unsigned short* __restrict__ xb,
                      const unsigned short* __restrict__ meanb,
                      const float* __restrict__ Wl, const float* __restrict__ bl,
                      const float* __restrict__ Wr,
                      unsigned short* __restrict__ h_out,
                      const int* __restrict__ batch, float* __restrict__ out,
                      int n_nodes, int final_layer) {
    const int lane = threadIdx.x & 63;
    const int c = lane & 15;     // feat%16 (B,C) / node%16 (A)
    const int q = lane >> 4;     // k-chunk selector / node-quarter (C)

    // ---- B fragments: [Wl | Wr] as K=128 x N=64, bf16, in registers ----
    bf16x8 B[4][4];              // [n-tile][k-step]
#pragma unroll
    for (int n = 0; n < 4; ++n) {
        const int feat = n * 16 + c;
#pragma unroll
        for (int t = 0; t < 4; ++t) {
            const float* Wsrc = (t < 2) ? Wl : Wr;
            const int k0 = (t & 1) * 32 + q * 8;
            const float4* wp = reinterpret_cast<const float4*>(&Wsrc[feat * 64 + k0]);
            float4 w0 = wp[0], w1 = wp[1];
            bf16x8 f;
            f[0] = (short)f2bf(w0.x); f[1] = (short)f2bf(w0.y);
            f[2] = (short)f2bf(w0.z); f[3] = (short)f2bf(w0.w);
            f[4] = (short)f2bf(w1.x); f[5] = (short)f2bf(w1.y);
            f[6] = (short)f2bf(w1.z); f[7] = (short)f2bf(w1.w);
            B[n][t] = f;
        }
    }
    float blv[4];
#pragma unroll
    for (int n = 0; n < 4; ++n) blv[n] = bl[n * 16 + c];

    const int tiles = (n_nodes + 15) >> 4;
    const int nw = gridDim.x * 4;
    const int gw = blockIdx.x * 4 + (int)(threadIdx.x >> 6);

    for (int tile = gw; tile < tiles; tile += nw) {
        const int base = tile << 4;
        const int nodeA = min(base + c, n_nodes - 1);   // A-operand row
        const uint4* mrow = reinterpret_cast<const uint4*>(&meanb[(size_t)nodeA * 64]);
        const uint4* xrow = reinterpret_cast<const uint4*>(&xb[(size_t)nodeA * 64]);
        bf16x8 A0 = __builtin_bit_cast(bf16x8, mrow[q]);        // k 0..31
        bf16x8 A1 = __builtin_bit_cast(bf16x8, mrow[4 + q]);    // k 32..63
        bf16x8 A2 = __builtin_bit_cast(bf16x8, xrow[q]);        // k 64..95
        bf16x8 A3 = __builtin_bit_cast(bf16x8, xrow[4 + q]);    // k 96..127

        f32x4 acc[4];
#pragma unroll
        for (int n = 0; n < 4; ++n) acc[n] = (f32x4){0.f, 0.f, 0.f, 0.f};

#pragma unroll
        for (int n = 0; n < 4; ++n) {
            acc[n] = __builtin_amdgcn_mfma_f32_16x16x32_bf16(A0, B[n][0], acc[n], 0, 0, 0);
            acc[n] = __builtin_amdgcn_mfma_f32_16x16x32_bf16(A1, B[n][1], acc[n], 0, 0, 0);
            acc[n] = __builtin_amdgcn_mfma_f32_16x16x32_bf16(A2, B[n][2], acc[n], 0, 0, 0);
            acc[n] = __builtin_amdgcn_mfma_f32_16x16x32_bf16(A3, B[n][3], acc[n], 0, 0, 0);
        }

        // ---- epilogue: bias, rowwise L2 norm, relu, store ----
        float ss[4] = {0.f, 0.f, 0.f, 0.f};
#pragma unroll
        for (int n = 0; n < 4; ++n)
#pragma unroll
            for (int r = 0; r < 4; ++r) {
                float t = acc[n][r] + blv[n];
                ss[r] += t * t;
            }
        // reduce over the 16 lanes of this quarter (feature dim); offsets<16
#pragma unroll
        for (int off = 1; off < 16; off <<= 1)
#pragma unroll
            for (int r = 0; r < 4; ++r) ss[r] += __shfl_xor(ss[r], off, 64);

#pragma unroll
        for (int r = 0; r < 4; ++r) {
            const float inv = 1.0f / fmaxf(sqrtf(ss[r]), 1e-12f);
            const int node = base + q * 4 + r;
            if (node < n_nodes) {
                if (final_layer) {
                    const int gb = batch[node];
#pragma unroll
                    for (int n = 0; n < 4; ++n) {
                        float o = fmaxf((acc[n][r] + blv[n]) * inv, 0.0f);
                        atomicAdd(&out[(size_t)gb * DFEAT + n * 16 + c], o);
                    }
                } else {
#pragma unroll
                    for (int n = 0; n < 4; ++n) {
                        float o = fmaxf((acc[n][r] + blv[n]) * inv, 0.0f);
                        h_out[(size_t)node * DFEAT + n * 16 + c] = f2bf(o);
                    }
                }
            }
        }
    }
}

// ============================================================================
extern "C" void kernel_launch(void* const* d_in, const int* in_sizes, int n_in,
                              void* d_out, int out_size, void* d_ws, size_t ws_size,
                              hipStream_t stream) {
    const float* x_raw = (const float*)d_in[0];
    const int*   eidx  = (const int*)d_in[1];
    const int*   batch = (const int*)d_in[2];
    const float* Wl0 = (const float*)d_in[3];
    const float* bl0 = (const float*)d_in[4];
    const float* Wr0 = (const float*)d_in[5];
    const float* Wl1 = (const float*)d_in[6];
    const float* bl1 = (const float*)d_in[7];
    const float* Wr1 = (const float*)d_in[8];
    const float* Wl2 = (const float*)d_in[9];
    const float* bl2 = (const float*)d_in[10];
    const float* Wr2 = (const float*)d_in[11];

    const int N = in_sizes[0] / DFEAT;
    const int E = in_sizes[1] / 2;
    const int* srcs = eidx;
    const int* dsts = eidx + E;
    float* out = (float*)d_out;

    const int NB = (N + 255) >> 8;   // buckets of 256 nodes; N=100000 -> 391 (<=512)

    char* ws = (char*)d_ws;
    auto align512 = [](size_t v) { return (v + 511) & ~(size_t)511; };
    size_t off = 0;
    int* rowptr = (int*)(ws + off); off += align512(((size_t)N + 1) * 4);
    int* col    = (int*)(ws + off); off += align512((size_t)E * 4);
    int* bhist  = (int*)(ws + off); off += align512(512 * 4);
    int* bbase  = (int*)(ws + off); off += align512(513 * 4);
    int* bcur   = (int*)(ws + off); off += align512(512 * 4);
    unsigned short* xb    = (unsigned short*)(ws + off); off += align512((size_t)N * DFEAT * 2);
    unsigned short* meanb = (unsigned short*)(ws + off); off += align512((size_t)N * DFEAT * 2);
    unsigned short* hA    = (unsigned short*)(ws + off); off += align512((size_t)N * DFEAT * 2);
    unsigned short* hB    = (unsigned short*)(ws + off);
    // pairbuf only lives during CSR build, which completes before hA is first
    // written (layer-0 transform) -> alias it onto hA. E*4 (6.4MB) <= N*128B.
    unsigned int* pairbuf = (unsigned int*)hA;

    hipMemsetAsync(bhist, 0, 512 * 4, stream);
    hipMemsetAsync(out, 0, (size_t)out_size * 4, stream);

    // input fp32 -> bf16 (once)
    const int n4 = N * DFEAT / 4;
    cvt_bf16_kernel<<<(n4 + 255) / 256, 256, 0, stream>>>(x_raw, xb, n4);

    // CSR build, binned two-pass (once)
    bucket_hist_kernel<<<512, 256, 0, stream>>>(dsts, bhist, E);
    bucket_scan_kernel<<<1, 256, 0, stream>>>(bhist, bbase, bcur);
    bin_kernel<<<(E + BIN_CH - 1) / BIN_CH, 256, 0, stream>>>(srcs, dsts, bcur, pairbuf, E);
    bucket_fill_kernel<<<NB, 256, 0, stream>>>(pairbuf, bbase, rowptr, col, N, E);

    const int gatherBlocks = (N + 3) / 4;
    // transform: one wave per 16-node tile, ~2 tiles per wave
    const int tiles    = (N + 15) / 16;
    const int xfBlocks = (tiles / 2 + 3) / 4 + 1;

    // ---- layer 0
    gather_mean_kernel<<<gatherBlocks, 256, 0, stream>>>(xb, rowptr, col, meanb, N);
    transform_mfma_kernel<<<xfBlocks, 256, 0, stream>>>(xb, meanb, Wl0, bl0, Wr0,
                                                        hA, nullptr, nullptr, N, 0);
    // ---- layer 1
    gather_mean_kernel<<<gatherBlocks, 256, 0, stream>>>(hA, rowptr, col, meanb, N);
    transform_mfma_kernel<<<xfBlocks, 256, 0, stream>>>(hA, meanb, Wl1, bl1, Wr1,
                                                        hB, nullptr, nullptr, N, 0);
    // ---- layer 2
    gather_mean_kernel<<<gatherBlocks, 256, 0, stream>>>(hB, rowptr, col, meanb, N);
    transform_mfma_kernel<<<xfBlocks, 256, 0, stream>>>(hB, meanb, Wl2, bl2, Wr2,
                                                        nullptr, batch, out, N, 1);
}

// Round 3
// 623.358 us; speedup vs baseline: 1.0897x; 1.0897x over previous
//
#include <hip/hip_runtime.h>

#define DFEAT 64

typedef __attribute__((ext_vector_type(8))) short bf16x8;   // 8 bf16 = 4 VGPRs
typedef __attribute__((ext_vector_type(4))) float f32x4;

// ---------------- bf16 helpers (OCP bfloat16, RNE pack) ----------------
__device__ __forceinline__ float bfhi(unsigned int u) {   // high 16 bits as bf16
    return __builtin_bit_cast(float, u & 0xFFFF0000u);
}
__device__ __forceinline__ float bflo(unsigned int u) {   // low 16 bits as bf16
    return __builtin_bit_cast(float, u << 16);
}
__device__ __forceinline__ unsigned short f2bf(float f) { // RNE
    unsigned int u = __builtin_bit_cast(unsigned int, f);
    u += 0x7FFFu + ((u >> 16) & 1u);
    return (unsigned short)(u >> 16);
}
__device__ __forceinline__ float4 upk4(uint2 v) {         // 4 bf16 -> 4 fp32
    float4 r;
    r.x = bflo(v.x); r.y = bfhi(v.x);
    r.z = bflo(v.y); r.w = bfhi(v.y);
    return r;
}

// ============================================================================
// fp32 -> bf16 conversion of the input features (once per call)
// ============================================================================
__global__ void __launch_bounds__(256)
cvt_bf16_kernel(const float* __restrict__ in, unsigned short* __restrict__ outb,
                int n4) {   // n4 = total elements / 4
    int i = blockIdx.x * 256 + threadIdx.x;
    if (i >= n4) return;
    const float4 v = reinterpret_cast<const float4*>(in)[i];
    uint2 p;
    p.x = (unsigned int)f2bf(v.x) | ((unsigned int)f2bf(v.y) << 16);
    p.y = (unsigned int)f2bf(v.z) | ((unsigned int)f2bf(v.w) << 16);
    reinterpret_cast<uint2*>(outb)[i] = p;
}

// ============================================================================
// CSR build, binned two-pass.
// Bucket b = 256 consecutive dst nodes. NB = ceil(N/256) <= 512 (N=100000).
// Edges pack into u32: (dst & 255) << 24 | src   (needs src < 2^24).
// ============================================================================

__global__ void __launch_bounds__(256)
bucket_hist_kernel(const int* __restrict__ dsts, int* __restrict__ bhist, int E) {
    __shared__ int h[512];
    const int tid = threadIdx.x;
    h[tid] = 0; h[tid + 256] = 0;
    __syncthreads();
    for (int e = blockIdx.x * 256 + tid; e < E; e += gridDim.x * 256)
        atomicAdd(&h[dsts[e] >> 8], 1);
    __syncthreads();
    for (int b = tid; b < 512; b += 256)
        if (h[b]) atomicAdd(&bhist[b], h[b]);
}

__global__ void __launch_bounds__(256)
bucket_scan_kernel(const int* __restrict__ bhist, int* __restrict__ bbase,
                   int* __restrict__ bcur) {
    __shared__ int sm[512];
    const int tid = threadIdx.x;
    sm[tid] = bhist[tid]; sm[tid + 256] = bhist[tid + 256];
    __syncthreads();
    for (int s = 1; s < 512; s <<= 1) {
        int a0 = (tid >= s) ? sm[tid - s] : 0;
        int a1 = sm[tid + 256 - s];
        __syncthreads();
        sm[tid] += a0; sm[tid + 256] += a1;
        __syncthreads();
    }
    for (int b = tid; b < 512; b += 256) {
        int excl = b ? sm[b - 1] : 0;
        bbase[b] = excl; bcur[b] = excl;
    }
    if (tid == 0) bbase[512] = sm[511];
}

#define BIN_CH 2048
__global__ void __launch_bounds__(256)
bin_kernel(const int* __restrict__ srcs, const int* __restrict__ dsts,
           int* __restrict__ bcur, unsigned int* __restrict__ pairbuf, int E) {
    __shared__ int hist[512];
    __shared__ int sscan[512];
    __shared__ int gbase[512];
    __shared__ unsigned int staged[BIN_CH];
    __shared__ unsigned short sbkt[BIN_CH];

    const int tid = threadIdx.x;
    const int base = blockIdx.x * BIN_CH;
    const int chcnt = min(BIN_CH, E - base);

    hist[tid] = 0; hist[tid + 256] = 0;
    __syncthreads();

    unsigned int pk[8];
    unsigned short bb[8], rr[8];
#pragma unroll
    for (int k = 0; k < 8; ++k) {
        int i = k * 256 + tid;
        if (i < chcnt) {
            int e = base + i;
            int d = dsts[e];
            int s = srcs[e];
            int b = d >> 8;
            int r = atomicAdd(&hist[b], 1);
            pk[k] = ((unsigned int)(d & 255) << 24) | (unsigned int)s;
            bb[k] = (unsigned short)b;
            rr[k] = (unsigned short)r;
        } else {
            bb[k] = 0xFFFFu;
        }
    }
    __syncthreads();

    sscan[tid] = hist[tid]; sscan[tid + 256] = hist[tid + 256];
    __syncthreads();
    for (int s = 1; s < 512; s <<= 1) {
        int a0 = (tid >= s) ? sscan[tid - s] : 0;
        int a1 = sscan[tid + 256 - s];
        __syncthreads();
        sscan[tid] += a0; sscan[tid + 256] += a1;
        __syncthreads();
    }

    for (int b = tid; b < 512; b += 256) {
        int c = hist[b];
        gbase[b] = c ? atomicAdd(&bcur[b], c) : 0;
    }
    __syncthreads();

#pragma unroll
    for (int k = 0; k < 8; ++k) {
        if (bb[k] != 0xFFFFu) {
            int b = bb[k];
            int lpos = (b ? sscan[b - 1] : 0) + rr[k];
            staged[lpos] = pk[k];
            sbkt[lpos] = (unsigned short)b;
        }
    }
    __syncthreads();

    for (int i = tid; i < chcnt; i += 256) {
        int b = sbkt[i];
        int excl = b ? sscan[b - 1] : 0;
        pairbuf[gbase[b] + (i - excl)] = staged[i];
    }
}

__global__ void __launch_bounds__(256)
bucket_fill_kernel(const unsigned int* __restrict__ pairbuf,
                   const int* __restrict__ bbase,
                   int* __restrict__ rowptr, int* __restrict__ col,
                   int N, int E) {
    __shared__ int hist[256];
    __shared__ int scan_[256];
    __shared__ int cur[256];

    const int tid = threadIdx.x;
    const int b = blockIdx.x;
    const int node0 = b << 8;
    const int bb0 = bbase[b];
    const int cnt = bbase[b + 1] - bb0;

    hist[tid] = 0;
    __syncthreads();
    for (int i = tid; i < cnt; i += 256)
        atomicAdd(&hist[pairbuf[bb0 + i] >> 24], 1);
    __syncthreads();

    scan_[tid] = hist[tid];
    __syncthreads();
    for (int s = 1; s < 256; s <<= 1) {
        int a = (tid >= s) ? scan_[tid - s] : 0;
        __syncthreads();
        scan_[tid] += a;
        __syncthreads();
    }
    int excl = tid ? scan_[tid - 1] : 0;
    if (node0 + tid < N) rowptr[node0 + tid] = bb0 + excl;
    if (b == 0 && tid == 0) rowptr[N] = E;
    cur[tid] = bb0 + excl;
    __syncthreads();

    for (int i = tid; i < cnt; i += 256) {
        unsigned int p = pairbuf[bb0 + i];
        int pos = atomicAdd(&cur[p >> 24], 1);
        col[pos] = (int)(p & 0xFFFFFFu);
    }
}

// ============================================================================
// Gather-mean over bf16 feature rows (128 B each). One wave per node.
// ============================================================================
__global__ void __launch_bounds__(256)
gather_mean_kernel(const unsigned short* __restrict__ xb,
                   const int* __restrict__ rowptr, const int* __restrict__ col,
                   unsigned short* __restrict__ meanb, int N) {
    int w = (blockIdx.x * 256 + threadIdx.x) >> 6;
    if (w >= N) return;
    const int lane = threadIdx.x & 63;
    const int r = lane >> 4;
    const int c = lane & 15;
    const uint2* x2 = reinterpret_cast<const uint2*>(xb);
    uint2* mean2 = reinterpret_cast<uint2*>(meanb);

    int st = rowptr[w], en = rowptr[w + 1];
    int deg = en - st;

    if (deg == 0) {
        if (r == 0) mean2[(size_t)w * 16 + c] = make_uint2(0, 0);
        return;
    }

    int nb = col[st + min(lane, deg - 1)];
    float4 acc = make_float4(0, 0, 0, 0);

#pragma unroll
    for (int k = 0; k < 4; ++k) {            // slots 0..15 (always)
        int i = 4 * k + r;
        int q = __shfl(nb, min(i, deg - 1), 64);
        float4 v = upk4(x2[(size_t)q * 16 + c]);
        float m = (i < deg) ? 1.0f : 0.0f;
        acc.x += v.x * m; acc.y += v.y * m; acc.z += v.z * m; acc.w += v.w * m;
    }
    if (deg > 16) {                          // slots 16..31
#pragma unroll
        for (int k = 4; k < 8; ++k) {
            int i = 4 * k + r;
            int q = __shfl(nb, min(i, deg - 1), 64);
            float4 v = upk4(x2[(size_t)q * 16 + c]);
            float m = (i < deg) ? 1.0f : 0.0f;
            acc.x += v.x * m; acc.y += v.y * m; acc.z += v.z * m; acc.w += v.w * m;
        }
    }
    if (deg > 32) {                          // slots 32..63 (rare)
#pragma unroll
        for (int k = 8; k < 16; ++k) {
            int i = 4 * k + r;
            int q = __shfl(nb, min(i, deg - 1), 64);
            float4 v = upk4(x2[(size_t)q * 16 + c]);
            float m = (i < deg) ? 1.0f : 0.0f;
            acc.x += v.x * m; acc.y += v.y * m; acc.z += v.z * m; acc.w += v.w * m;
        }
    }
    for (int base = 64; base < deg; base += 64) {   // ultra-rare tail
        int cnt = deg - base;
        int nb2 = col[st + base + min(lane, cnt - 1)];
#pragma unroll
        for (int k = 0; k < 16; ++k) {
            int i = 4 * k + r;
            int q = __shfl(nb2, min(i, cnt - 1), 64);
            float4 v = upk4(x2[(size_t)q * 16 + c]);
            float m = (i < cnt) ? 1.0f : 0.0f;
            acc.x += v.x * m; acc.y += v.y * m; acc.z += v.z * m; acc.w += v.w * m;
        }
    }

#pragma unroll
    for (int off = 16; off <= 32; off <<= 1) {
        acc.x += __shfl_xor(acc.x, off, 64);
        acc.y += __shfl_xor(acc.y, off, 64);
        acc.z += __shfl_xor(acc.z, off, 64);
        acc.w += __shfl_xor(acc.w, off, 64);
    }
    float inv = 1.0f / (float)deg;
    if (r == 0) {
        uint2 p;
        p.x = (unsigned int)f2bf(acc.x * inv) | ((unsigned int)f2bf(acc.y * inv) << 16);
        p.y = (unsigned int)f2bf(acc.z * inv) | ((unsigned int)f2bf(acc.w * inv) << 16);
        mean2[(size_t)w * 16 + c] = p;
    }
}

// ============================================================================
// MFMA transform: out = [mean|x] @ [Wl|Wr]^T + bl; L2norm; ReLU.
// Weights are staged ONCE per block into LDS as bf16 MFMA B-fragments,
// fragment-major (frag f = n*4+t, 64 lanes x 16B each) so each lane's
// ds_read_b128 is its own contiguous 16B -> conflict-free. Tile loop reads
// 4 frags per n right before the MFMAs: ~60 live VGPRs, no scratch.
// __launch_bounds__(256,4) caps VGPRs at 128 so even a fully-hoisted
// schedule (B resident, ~116 VGPRs) cannot spill.
// mfma_f32_16x16x32_bf16: A row=lane&15 (node), k=(lane>>4)*8+j;
//                         B col=lane&15 (feat), k=(lane>>4)*8+j;
//                         C/D col=lane&15 (feat), row=(lane>>4)*4+reg (node).
// ============================================================================
__global__ void __launch_bounds__(256, 4)
transform_mfma_kernel(const unsigned short* __restrict__ xb,
                      const unsigned short* __restrict__ meanb,
                      const float* __restrict__ Wl, const float* __restrict__ bl,
                      const float* __restrict__ Wr,
                      unsigned short* __restrict__ h_out,
                      const int* __restrict__ batch, float* __restrict__ out,
                      int n_nodes, int final_layer) {
    __shared__ __align__(16) unsigned short Wlds[8192];   // 16 frags * 512 ushort

    const int tid = threadIdx.x;

    // ---- stage [Wl|Wr] -> bf16 fragments in LDS (once per block) ----
    // source element (feat,k) of Wsrc -> frag f=(feat>>4)*4 + isWr*2 + (k>>5),
    // lane = ((k>>3)&3)*16 + (feat&15), elem j = k&7.
    for (int i4 = tid; i4 < 1024; i4 += 256) {
        const float4 wl = reinterpret_cast<const float4*>(Wl)[i4];
        const float4 wr = reinterpret_cast<const float4*>(Wr)[i4];
        const int feat = i4 >> 4;
        const int n = feat >> 4, cc = feat & 15;
        const int k0 = (i4 & 15) << 2;           // 4 consecutive k, same octet half
        const int q = (k0 >> 3) & 3, tl = k0 >> 5, j0 = k0 & 7;
        const int lofs = (q * 16 + cc) * 8 + j0;
        unsigned short* d0 = &Wlds[(n * 4 + tl) * 512 + lofs];
        d0[0] = f2bf(wl.x); d0[1] = f2bf(wl.y); d0[2] = f2bf(wl.z); d0[3] = f2bf(wl.w);
        unsigned short* d1 = &Wlds[(n * 4 + 2 + tl) * 512 + lofs];
        d1[0] = f2bf(wr.x); d1[1] = f2bf(wr.y); d1[2] = f2bf(wr.z); d1[3] = f2bf(wr.w);
    }
    __syncthreads();

    const int lane = tid & 63;
    const int c = lane & 15;     // feat%16 (B,C) / node%16 (A)
    const int q = lane >> 4;     // k-chunk selector / node-quarter (C)
    const bf16x8* fragp = reinterpret_cast<const bf16x8*>(Wlds);  // [f*64 + lane]

    float blv[4];
#pragma unroll
    for (int n = 0; n < 4; ++n) blv[n] = bl[n * 16 + c];

    const int tiles = (n_nodes + 15) >> 4;
    const int nw = gridDim.x * 4;
    const int gw = blockIdx.x * 4 + (tid >> 6);

    for (int tile = gw; tile < tiles; tile += nw) {
        const int base = tile << 4;
        const int nodeA = min(base + c, n_nodes - 1);   // A-operand row
        const uint4* mrow = reinterpret_cast<const uint4*>(&meanb[(size_t)nodeA * 64]);
        const uint4* xrow = reinterpret_cast<const uint4*>(&xb[(size_t)nodeA * 64]);
        bf16x8 A0 = __builtin_bit_cast(bf16x8, mrow[q]);        // k 0..31
        bf16x8 A1 = __builtin_bit_cast(bf16x8, mrow[4 + q]);    // k 32..63
        bf16x8 A2 = __builtin_bit_cast(bf16x8, xrow[q]);        // k 64..95
        bf16x8 A3 = __builtin_bit_cast(bf16x8, xrow[4 + q]);    // k 96..127

        f32x4 acc[4];
#pragma unroll
        for (int n = 0; n < 4; ++n) acc[n] = (f32x4){0.f, 0.f, 0.f, 0.f};

#pragma unroll
        for (int n = 0; n < 4; ++n) {
            bf16x8 b0 = fragp[(n * 4 + 0) * 64 + lane];
            bf16x8 b1 = fragp[(n * 4 + 1) * 64 + lane];
            bf16x8 b2 = fragp[(n * 4 + 2) * 64 + lane];
            bf16x8 b3 = fragp[(n * 4 + 3) * 64 + lane];
            acc[n] = __builtin_amdgcn_mfma_f32_16x16x32_bf16(A0, b0, acc[n], 0, 0, 0);
            acc[n] = __builtin_amdgcn_mfma_f32_16x16x32_bf16(A1, b1, acc[n], 0, 0, 0);
            acc[n] = __builtin_amdgcn_mfma_f32_16x16x32_bf16(A2, b2, acc[n], 0, 0, 0);
            acc[n] = __builtin_amdgcn_mfma_f32_16x16x32_bf16(A3, b3, acc[n], 0, 0, 0);
        }

        // ---- epilogue: bias, rowwise L2 norm, relu, store ----
        float ss[4] = {0.f, 0.f, 0.f, 0.f};
#pragma unroll
        for (int n = 0; n < 4; ++n)
#pragma unroll
            for (int r = 0; r < 4; ++r) {
                float t = acc[n][r] + blv[n];
                ss[r] += t * t;
            }
        // reduce over the 16 lanes of this quarter (feature dim); offsets<16
#pragma unroll
        for (int off = 1; off < 16; off <<= 1)
#pragma unroll
            for (int r = 0; r < 4; ++r) ss[r] += __shfl_xor(ss[r], off, 64);

#pragma unroll
        for (int r = 0; r < 4; ++r) {
            const float inv = 1.0f / fmaxf(sqrtf(ss[r]), 1e-12f);
            const int node = base + q * 4 + r;
            if (node < n_nodes) {
                if (final_layer) {
                    const int gb = batch[node];
#pragma unroll
                    for (int n = 0; n < 4; ++n) {
                        float o = fmaxf((acc[n][r] + blv[n]) * inv, 0.0f);
                        atomicAdd(&out[(size_t)gb * DFEAT + n * 16 + c], o);
                    }
                } else {
#pragma unroll
                    for (int n = 0; n < 4; ++n) {
                        float o = fmaxf((acc[n][r] + blv[n]) * inv, 0.0f);
                        h_out[(size_t)node * DFEAT + n * 16 + c] = f2bf(o);
                    }
                }
            }
        }
    }
}

// ============================================================================
extern "C" void kernel_launch(void* const* d_in, const int* in_sizes, int n_in,
                              void* d_out, int out_size, void* d_ws, size_t ws_size,
                              hipStream_t stream) {
    const float* x_raw = (const float*)d_in[0];
    const int*   eidx  = (const int*)d_in[1];
    const int*   batch = (const int*)d_in[2];
    const float* Wl0 = (const float*)d_in[3];
    const float* bl0 = (const float*)d_in[4];
    const float* Wr0 = (const float*)d_in[5];
    const float* Wl1 = (const float*)d_in[6];
    const float* bl1 = (const float*)d_in[7];
    const float* Wr1 = (const float*)d_in[8];
    const float* Wl2 = (const float*)d_in[9];
    const float* bl2 = (const float*)d_in[10];
    const float* Wr2 = (const float*)d_in[11];

    const int N = in_sizes[0] / DFEAT;
    const int E = in_sizes[1] / 2;
    const int* srcs = eidx;
    const int* dsts = eidx + E;
    float* out = (float*)d_out;

    const int NB = (N + 255) >> 8;   // buckets of 256 nodes; N=100000 -> 391 (<=512)

    char* ws = (char*)d_ws;
    auto align512 = [](size_t v) { return (v + 511) & ~(size_t)511; };
    size_t off = 0;
    int* rowptr = (int*)(ws + off); off += align512(((size_t)N + 1) * 4);
    int* col    = (int*)(ws + off); off += align512((size_t)E * 4);
    int* bhist  = (int*)(ws + off); off += align512(512 * 4);
    int* bbase  = (int*)(ws + off); off += align512(513 * 4);
    int* bcur   = (int*)(ws + off); off += align512(512 * 4);
    unsigned short* xb    = (unsigned short*)(ws + off); off += align512((size_t)N * DFEAT * 2);
    unsigned short* meanb = (unsigned short*)(ws + off); off += align512((size_t)N * DFEAT * 2);
    unsigned short* hA    = (unsigned short*)(ws + off); off += align512((size_t)N * DFEAT * 2);
    unsigned short* hB    = (unsigned short*)(ws + off);
    // pairbuf only lives during CSR build, which completes before hA is first
    // written (layer-0 transform) -> alias it onto hA. E*4 (6.4MB) <= N*128B.
    unsigned int* pairbuf = (unsigned int*)hA;

    hipMemsetAsync(bhist, 0, 512 * 4, stream);
    hipMemsetAsync(out, 0, (size_t)out_size * 4, stream);

    // input fp32 -> bf16 (once)
    const int n4 = N * DFEAT / 4;
    cvt_bf16_kernel<<<(n4 + 255) / 256, 256, 0, stream>>>(x_raw, xb, n4);

    // CSR build, binned two-pass (once)
    bucket_hist_kernel<<<512, 256, 0, stream>>>(dsts, bhist, E);
    bucket_scan_kernel<<<1, 256, 0, stream>>>(bhist, bbase, bcur);
    bin_kernel<<<(E + BIN_CH - 1) / BIN_CH, 256, 0, stream>>>(srcs, dsts, bcur, pairbuf, E);
    bucket_fill_kernel<<<NB, 256, 0, stream>>>(pairbuf, bbase, rowptr, col, N, E);

    const int gatherBlocks = (N + 3) / 4;
    // transform: 4 waves/block, ~2 tiles per wave
    const int tiles    = (N + 15) / 16;
    const int xfBlocks = (tiles + 7) / 8;

    // ---- layer 0
    gather_mean_kernel<<<gatherBlocks, 256, 0, stream>>>(xb, rowptr, col, meanb, N);
    transform_mfma_kernel<<<xfBlocks, 256, 0, stream>>>(xb, meanb, Wl0, bl0, Wr0,
                                                        hA, nullptr, nullptr, N, 0);
    // ---- layer 1
    gather_mean_kernel<<<gatherBlocks, 256, 0, stream>>>(hA, rowptr, col, meanb, N);
    transform_mfma_kernel<<<xfBlocks, 256, 0, stream>>>(hA, meanb, Wl1, bl1, Wr1,
                                                        hB, nullptr, nullptr, N, 0);
    // ---- layer 2
    gather_mean_kernel<<<gatherBlocks, 256, 0, stream>>>(hB, rowptr, col, meanb, N);
    transform_mfma_kernel<<<xfBlocks, 256, 0, stream>>>(hB, meanb, Wl2, bl2, Wr2,
                                                        nullptr, batch, out, N, 1);
}

// Round 4
// 342.409 us; speedup vs baseline: 1.9838x; 1.8205x over previous
//
#include <hip/hip_runtime.h>

#define DFEAT 64

typedef __attribute__((ext_vector_type(8))) short bf16x8;   // 8 bf16 = 4 VGPRs
typedef __attribute__((ext_vector_type(4))) float f32x4;

// ---------------- bf16 helpers (OCP bfloat16, RNE pack) ----------------
__device__ __forceinline__ float bfhi(unsigned int u) {   // high 16 bits as bf16
    return __builtin_bit_cast(float, u & 0xFFFF0000u);
}
__device__ __forceinline__ float bflo(unsigned int u) {   // low 16 bits as bf16
    return __builtin_bit_cast(float, u << 16);
}
__device__ __forceinline__ unsigned short f2bf(float f) { // RNE
    unsigned int u = __builtin_bit_cast(unsigned int, f);
    u += 0x7FFFu + ((u >> 16) & 1u);
    return (unsigned short)(u >> 16);
}
__device__ __forceinline__ float4 upk4(uint2 v) {         // 4 bf16 -> 4 fp32
    float4 r;
    r.x = bflo(v.x); r.y = bfhi(v.x);
    r.z = bflo(v.y); r.w = bfhi(v.y);
    return r;
}

// ============================================================================
// fp32 -> bf16 conversion of the input features (once per call)
// ============================================================================
__global__ void __launch_bounds__(256)
cvt_bf16_kernel(const float* __restrict__ in, unsigned short* __restrict__ outb,
                int n4) {   // n4 = total elements / 4
    int i = blockIdx.x * 256 + threadIdx.x;
    if (i >= n4) return;
    const float4 v = reinterpret_cast<const float4*>(in)[i];
    uint2 p;
    p.x = (unsigned int)f2bf(v.x) | ((unsigned int)f2bf(v.y) << 16);
    p.y = (unsigned int)f2bf(v.z) | ((unsigned int)f2bf(v.w) << 16);
    reinterpret_cast<uint2*>(outb)[i] = p;
}

// ============================================================================
// CSR build, binned two-pass.
// Bucket b = 256 consecutive dst nodes. NB = ceil(N/256) <= 512 (N=100000).
// Edges pack into u32: (dst & 255) << 24 | src   (needs src < 2^24).
// ============================================================================

__global__ void __launch_bounds__(256)
bucket_hist_kernel(const int* __restrict__ dsts, int* __restrict__ bhist, int E) {
    __shared__ int h[512];
    const int tid = threadIdx.x;
    h[tid] = 0; h[tid + 256] = 0;
    __syncthreads();
    for (int e = blockIdx.x * 256 + tid; e < E; e += gridDim.x * 256)
        atomicAdd(&h[dsts[e] >> 8], 1);
    __syncthreads();
    for (int b = tid; b < 512; b += 256)
        if (h[b]) atomicAdd(&bhist[b], h[b]);
}

__global__ void __launch_bounds__(256)
bucket_scan_kernel(const int* __restrict__ bhist, int* __restrict__ bbase,
                   int* __restrict__ bcur) {
    __shared__ int sm[512];
    const int tid = threadIdx.x;
    sm[tid] = bhist[tid]; sm[tid + 256] = bhist[tid + 256];
    __syncthreads();
    for (int s = 1; s < 512; s <<= 1) {
        int a0 = (tid >= s) ? sm[tid - s] : 0;
        int a1 = sm[tid + 256 - s];
        __syncthreads();
        sm[tid] += a0; sm[tid + 256] += a1;
        __syncthreads();
    }
    for (int b = tid; b < 512; b += 256) {
        int excl = b ? sm[b - 1] : 0;
        bbase[b] = excl; bcur[b] = excl;
    }
    if (tid == 0) bbase[512] = sm[511];
}

#define BIN_CH 2048
__global__ void __launch_bounds__(256)
bin_kernel(const int* __restrict__ srcs, const int* __restrict__ dsts,
           int* __restrict__ bcur, unsigned int* __restrict__ pairbuf, int E) {
    __shared__ int hist[512];
    __shared__ int sscan[512];
    __shared__ int gbase[512];
    __shared__ unsigned int staged[BIN_CH];
    __shared__ unsigned short sbkt[BIN_CH];

    const int tid = threadIdx.x;
    const int base = blockIdx.x * BIN_CH;
    const int chcnt = min(BIN_CH, E - base);

    hist[tid] = 0; hist[tid + 256] = 0;
    __syncthreads();

    unsigned int pk[8];
    unsigned short bb[8], rr[8];
#pragma unroll
    for (int k = 0; k < 8; ++k) {
        int i = k * 256 + tid;
        if (i < chcnt) {
            int e = base + i;
            int d = dsts[e];
            int s = srcs[e];
            int b = d >> 8;
            int r = atomicAdd(&hist[b], 1);
            pk[k] = ((unsigned int)(d & 255) << 24) | (unsigned int)s;
            bb[k] = (unsigned short)b;
            rr[k] = (unsigned short)r;
        } else {
            bb[k] = 0xFFFFu;
        }
    }
    __syncthreads();

    sscan[tid] = hist[tid]; sscan[tid + 256] = hist[tid + 256];
    __syncthreads();
    for (int s = 1; s < 512; s <<= 1) {
        int a0 = (tid >= s) ? sscan[tid - s] : 0;
        int a1 = sscan[tid + 256 - s];
        __syncthreads();
        sscan[tid] += a0; sscan[tid + 256] += a1;
        __syncthreads();
    }

    for (int b = tid; b < 512; b += 256) {
        int c = hist[b];
        gbase[b] = c ? atomicAdd(&bcur[b], c) : 0;
    }
    __syncthreads();

#pragma unroll
    for (int k = 0; k < 8; ++k) {
        if (bb[k] != 0xFFFFu) {
            int b = bb[k];
            int lpos = (b ? sscan[b - 1] : 0) + rr[k];
            staged[lpos] = pk[k];
            sbkt[lpos] = (unsigned short)b;
        }
    }
    __syncthreads();

    for (int i = tid; i < chcnt; i += 256) {
        int b = sbkt[i];
        int excl = b ? sscan[b - 1] : 0;
        pairbuf[gbase[b] + (i - excl)] = staged[i];
    }
}

__global__ void __launch_bounds__(256)
bucket_fill_kernel(const unsigned int* __restrict__ pairbuf,
                   const int* __restrict__ bbase,
                   int* __restrict__ rowptr, int* __restrict__ col,
                   int N, int E) {
    __shared__ int hist[256];
    __shared__ int scan_[256];
    __shared__ int cur[256];

    const int tid = threadIdx.x;
    const int b = blockIdx.x;
    const int node0 = b << 8;
    const int bb0 = bbase[b];
    const int cnt = bbase[b + 1] - bb0;

    hist[tid] = 0;
    __syncthreads();
    for (int i = tid; i < cnt; i += 256)
        atomicAdd(&hist[pairbuf[bb0 + i] >> 24], 1);
    __syncthreads();

    scan_[tid] = hist[tid];
    __syncthreads();
    for (int s = 1; s < 256; s <<= 1) {
        int a = (tid >= s) ? scan_[tid - s] : 0;
        __syncthreads();
        scan_[tid] += a;
        __syncthreads();
    }
    int excl = tid ? scan_[tid - 1] : 0;
    if (node0 + tid < N) rowptr[node0 + tid] = bb0 + excl;
    if (b == 0 && tid == 0) rowptr[N] = E;
    cur[tid] = bb0 + excl;
    __syncthreads();

    for (int i = tid; i < cnt; i += 256) {
        unsigned int p = pairbuf[bb0 + i];
        int pos = atomicAdd(&cur[p >> 24], 1);
        col[pos] = (int)(p & 0xFFFFFFu);
    }
}

// ============================================================================
// Gather-mean over bf16 feature rows (128 B each). One wave per node.
// ============================================================================
__global__ void __launch_bounds__(256)
gather_mean_kernel(const unsigned short* __restrict__ xb,
                   const int* __restrict__ rowptr, const int* __restrict__ col,
                   unsigned short* __restrict__ meanb, int N) {
    int w = (blockIdx.x * 256 + threadIdx.x) >> 6;
    if (w >= N) return;
    const int lane = threadIdx.x & 63;
    const int r = lane >> 4;
    const int c = lane & 15;
    const uint2* x2 = reinterpret_cast<const uint2*>(xb);
    uint2* mean2 = reinterpret_cast<uint2*>(meanb);

    int st = rowptr[w], en = rowptr[w + 1];
    int deg = en - st;

    if (deg == 0) {
        if (r == 0) mean2[(size_t)w * 16 + c] = make_uint2(0, 0);
        return;
    }

    int nb = col[st + min(lane, deg - 1)];
    float4 acc = make_float4(0, 0, 0, 0);

#pragma unroll
    for (int k = 0; k < 4; ++k) {            // slots 0..15 (always)
        int i = 4 * k + r;
        int q = __shfl(nb, min(i, deg - 1), 64);
        float4 v = upk4(x2[(size_t)q * 16 + c]);
        float m = (i < deg) ? 1.0f : 0.0f;
        acc.x += v.x * m; acc.y += v.y * m; acc.z += v.z * m; acc.w += v.w * m;
    }
    if (deg > 16) {                          // slots 16..31
#pragma unroll
        for (int k = 4; k < 8; ++k) {
            int i = 4 * k + r;
            int q = __shfl(nb, min(i, deg - 1), 64);
            float4 v = upk4(x2[(size_t)q * 16 + c]);
            float m = (i < deg) ? 1.0f : 0.0f;
            acc.x += v.x * m; acc.y += v.y * m; acc.z += v.z * m; acc.w += v.w * m;
        }
    }
    if (deg > 32) {                          // slots 32..63 (rare)
#pragma unroll
        for (int k = 8; k < 16; ++k) {
            int i = 4 * k + r;
            int q = __shfl(nb, min(i, deg - 1), 64);
            float4 v = upk4(x2[(size_t)q * 16 + c]);
            float m = (i < deg) ? 1.0f : 0.0f;
            acc.x += v.x * m; acc.y += v.y * m; acc.z += v.z * m; acc.w += v.w * m;
        }
    }
    for (int base = 64; base < deg; base += 64) {   // ultra-rare tail
        int cnt = deg - base;
        int nb2 = col[st + base + min(lane, cnt - 1)];
#pragma unroll
        for (int k = 0; k < 16; ++k) {
            int i = 4 * k + r;
            int q = __shfl(nb2, min(i, cnt - 1), 64);
            float4 v = upk4(x2[(size_t)q * 16 + c]);
            float m = (i < cnt) ? 1.0f : 0.0f;
            acc.x += v.x * m; acc.y += v.y * m; acc.z += v.z * m; acc.w += v.w * m;
        }
    }

#pragma unroll
    for (int off = 16; off <= 32; off <<= 1) {
        acc.x += __shfl_xor(acc.x, off, 64);
        acc.y += __shfl_xor(acc.y, off, 64);
        acc.z += __shfl_xor(acc.z, off, 64);
        acc.w += __shfl_xor(acc.w, off, 64);
    }
    float inv = 1.0f / (float)deg;
    if (r == 0) {
        uint2 p;
        p.x = (unsigned int)f2bf(acc.x * inv) | ((unsigned int)f2bf(acc.y * inv) << 16);
        p.y = (unsigned int)f2bf(acc.z * inv) | ((unsigned int)f2bf(acc.w * inv) << 16);
        mean2[(size_t)w * 16 + c] = p;
    }
}

// ============================================================================
// MFMA transform, W-as-A orientation: D = [Wl|Wr] @ [mean|x]^T  (+bl, L2, relu)
// A = weight fragments from LDS (row=lane&15 -> out-feature), B = node
// features (col=lane&15 -> node). C/D: col=lane&15=NODE, row=(lane>>4)*4+reg
// = feature within 16-block -> lane (q,c) holds node base+c, features
// 16n+4q+{0..3}: 4 CONSECUTIVE bf16 -> one uint2 store per n (coalesced),
// and the L2-norm reduce is 2 shfl_xor (16,32) across q-groups.
// One tile (16 nodes) per wave; wave ends after its stores (no vmcnt
// drain coupling into a next iteration). Final layer: batch is sorted ->
// tile is ~always graph-uniform -> wave-reduce, 16 atomics/wave.
// ============================================================================
__global__ void __launch_bounds__(256, 4)
transform_mfma_kernel(const unsigned short* __restrict__ xb,
                      const unsigned short* __restrict__ meanb,
                      const float* __restrict__ Wl, const float* __restrict__ bl,
                      const float* __restrict__ Wr,
                      unsigned short* __restrict__ h_out,
                      const int* __restrict__ batch, float* __restrict__ out,
                      int n_nodes, int final_layer) {
    __shared__ __align__(16) unsigned short Wlds[8192];   // 16 frags * 512 ushort

    const int tid = threadIdx.x;

    // ---- stage [Wl|Wr] -> bf16 fragments in LDS (once per block) ----
    // element (feat,k) of Wsrc -> frag f=(feat>>4)*4 + isWr*2 + (k>>5),
    // lane = ((k>>3)&3)*16 + (feat&15), elem j = k&7.   (A-row == B-col map)
    for (int i4 = tid; i4 < 1024; i4 += 256) {
        const float4 wl = reinterpret_cast<const float4*>(Wl)[i4];
        const float4 wr = reinterpret_cast<const float4*>(Wr)[i4];
        const int feat = i4 >> 4;
        const int n = feat >> 4, cc = feat & 15;
        const int k0 = (i4 & 15) << 2;           // 4 consecutive k, same octet half
        const int qq = (k0 >> 3) & 3, tl = k0 >> 5, j0 = k0 & 7;
        const int lofs = (qq * 16 + cc) * 8 + j0;
        unsigned short* d0 = &Wlds[(n * 4 + tl) * 512 + lofs];
        d0[0] = f2bf(wl.x); d0[1] = f2bf(wl.y); d0[2] = f2bf(wl.z); d0[3] = f2bf(wl.w);
        unsigned short* d1 = &Wlds[(n * 4 + 2 + tl) * 512 + lofs];
        d1[0] = f2bf(wr.x); d1[1] = f2bf(wr.y); d1[2] = f2bf(wr.z); d1[3] = f2bf(wr.w);
    }
    __syncthreads();

    const int tiles = (n_nodes + 15) >> 4;
    const int tile = blockIdx.x * 4 + (tid >> 6);
    if (tile >= tiles) return;               // after the only barrier: safe

    const int lane = tid & 63;
    const int c = lane & 15;     // node within tile (B col / C col)
    const int q = lane >> 4;     // k-octet (A/B) / feature quarter (C row)
    const bf16x8* fragp = reinterpret_cast<const bf16x8*>(Wlds);  // [f*64 + lane]

    const int base = tile << 4;
    const int nodeB = min(base + c, n_nodes - 1);
    const bool valid = (base + c) < n_nodes;

    const uint4* mrow = reinterpret_cast<const uint4*>(&meanb[(size_t)nodeB * 64]);
    const uint4* xrow = reinterpret_cast<const uint4*>(&xb[(size_t)nodeB * 64]);
    bf16x8 F0 = __builtin_bit_cast(bf16x8, mrow[q]);        // k 0..31   (mean)
    bf16x8 F1 = __builtin_bit_cast(bf16x8, mrow[4 + q]);    // k 32..63  (mean)
    bf16x8 F2 = __builtin_bit_cast(bf16x8, xrow[q]);        // k 64..95  (x)
    bf16x8 F3 = __builtin_bit_cast(bf16x8, xrow[4 + q]);    // k 96..127 (x)

    f32x4 acc[4];
#pragma unroll
    for (int n = 0; n < 4; ++n) acc[n] = (f32x4){0.f, 0.f, 0.f, 0.f};

#pragma unroll
    for (int n = 0; n < 4; ++n) {
        bf16x8 w0 = fragp[(n * 4 + 0) * 64 + lane];   // Wl, k 0..31
        bf16x8 w1 = fragp[(n * 4 + 1) * 64 + lane];   // Wl, k 32..63
        bf16x8 w2 = fragp[(n * 4 + 2) * 64 + lane];   // Wr, k 0..31
        bf16x8 w3 = fragp[(n * 4 + 3) * 64 + lane];   // Wr, k 32..63
        acc[n] = __builtin_amdgcn_mfma_f32_16x16x32_bf16(w0, F0, acc[n], 0, 0, 0);
        acc[n] = __builtin_amdgcn_mfma_f32_16x16x32_bf16(w1, F1, acc[n], 0, 0, 0);
        acc[n] = __builtin_amdgcn_mfma_f32_16x16x32_bf16(w2, F2, acc[n], 0, 0, 0);
        acc[n] = __builtin_amdgcn_mfma_f32_16x16x32_bf16(w3, F3, acc[n], 0, 0, 0);
    }

    // ---- epilogue: bias, L2 norm over features (this lane's node), relu ----
    float v[4][4];
    float ss = 0.f;
#pragma unroll
    for (int n = 0; n < 4; ++n) {
        const float4 b4 = reinterpret_cast<const float4*>(bl)[n * 4 + q]; // feats 16n+4q+..
        v[n][0] = acc[n][0] + b4.x;
        v[n][1] = acc[n][1] + b4.y;
        v[n][2] = acc[n][2] + b4.z;
        v[n][3] = acc[n][3] + b4.w;
#pragma unroll
        for (int r = 0; r < 4; ++r) ss += v[n][r] * v[n][r];
    }
    ss += __shfl_xor(ss, 16, 64);
    ss += __shfl_xor(ss, 32, 64);
    const float inv = 1.0f / fmaxf(sqrtf(ss), 1e-12f);

    if (!final_layer) {
        if (valid) {
            uint2* dst = reinterpret_cast<uint2*>(&h_out[(size_t)(base + c) * 64]);
#pragma unroll
            for (int n = 0; n < 4; ++n) {
                float o0 = fmaxf(v[n][0] * inv, 0.f), o1 = fmaxf(v[n][1] * inv, 0.f);
                float o2 = fmaxf(v[n][2] * inv, 0.f), o3 = fmaxf(v[n][3] * inv, 0.f);
                uint2 p;
                p.x = (unsigned int)f2bf(o0) | ((unsigned int)f2bf(o1) << 16);
                p.y = (unsigned int)f2bf(o2) | ((unsigned int)f2bf(o3) << 16);
                dst[n * 4 + q] = p;       // ushorts (base+c)*64 + 16n + 4q ..
            }
        }
    } else {
        float o[4][4];
#pragma unroll
        for (int n = 0; n < 4; ++n)
#pragma unroll
            for (int r = 0; r < 4; ++r)
                o[n][r] = valid ? fmaxf(v[n][r] * inv, 0.f) : 0.f;

        const int lastn = min(base + 15, n_nodes - 1);
        const int gb0 = batch[base];
        if (gb0 == batch[lastn]) {
            // graph-uniform tile: reduce over the 16 nodes, 1 atomic per feat
#pragma unroll
            for (int n = 0; n < 4; ++n)
#pragma unroll
                for (int r = 0; r < 4; ++r) {
                    float s = o[n][r];
                    s += __shfl_xor(s, 1, 64);
                    s += __shfl_xor(s, 2, 64);
                    s += __shfl_xor(s, 4, 64);
                    s += __shfl_xor(s, 8, 64);
                    if (c == 0)
                        atomicAdd(&out[(size_t)gb0 * DFEAT + n * 16 + q * 4 + r], s);
                }
        } else {
            if (valid) {
                const int gb = batch[base + c];
#pragma unroll
                for (int n = 0; n < 4; ++n)
#pragma unroll
                    for (int r = 0; r < 4; ++r)
                        atomicAdd(&out[(size_t)gb * DFEAT + n * 16 + q * 4 + r], o[n][r]);
            }
        }
    }
}

// ============================================================================
extern "C" void kernel_launch(void* const* d_in, const int* in_sizes, int n_in,
                              void* d_out, int out_size, void* d_ws, size_t ws_size,
                              hipStream_t stream) {
    const float* x_raw = (const float*)d_in[0];
    const int*   eidx  = (const int*)d_in[1];
    const int*   batch = (const int*)d_in[2];
    const float* Wl0 = (const float*)d_in[3];
    const float* bl0 = (const float*)d_in[4];
    const float* Wr0 = (const float*)d_in[5];
    const float* Wl1 = (const float*)d_in[6];
    const float* bl1 = (const float*)d_in[7];
    const float* Wr1 = (const float*)d_in[8];
    const float* Wl2 = (const float*)d_in[9];
    const float* bl2 = (const float*)d_in[10];
    const float* Wr2 = (const float*)d_in[11];

    const int N = in_sizes[0] / DFEAT;
    const int E = in_sizes[1] / 2;
    const int* srcs = eidx;
    const int* dsts = eidx + E;
    float* out = (float*)d_out;

    const int NB = (N + 255) >> 8;   // buckets of 256 nodes; N=100000 -> 391 (<=512)

    char* ws = (char*)d_ws;
    auto align512 = [](size_t v) { return (v + 511) & ~(size_t)511; };
    size_t off = 0;
    int* rowptr = (int*)(ws + off); off += align512(((size_t)N + 1) * 4);
    int* col    = (int*)(ws + off); off += align512((size_t)E * 4);
    int* bhist  = (int*)(ws + off); off += align512(512 * 4);
    int* bbase  = (int*)(ws + off); off += align512(513 * 4);
    int* bcur   = (int*)(ws + off); off += align512(512 * 4);
    unsigned short* xb    = (unsigned short*)(ws + off); off += align512((size_t)N * DFEAT * 2);
    unsigned short* meanb = (unsigned short*)(ws + off); off += align512((size_t)N * DFEAT * 2);
    unsigned short* hA    = (unsigned short*)(ws + off); off += align512((size_t)N * DFEAT * 2);
    unsigned short* hB    = (unsigned short*)(ws + off);
    // pairbuf only lives during CSR build, which completes before hA is first
    // written (layer-0 transform) -> alias it onto hA. E*4 (6.4MB) <= N*128B.
    unsigned int* pairbuf = (unsigned int*)hA;

    hipMemsetAsync(bhist, 0, 512 * 4, stream);
    hipMemsetAsync(out, 0, (size_t)out_size * 4, stream);

    // input fp32 -> bf16 (once)
    const int n4 = N * DFEAT / 4;
    cvt_bf16_kernel<<<(n4 + 255) / 256, 256, 0, stream>>>(x_raw, xb, n4);

    // CSR build, binned two-pass (once)
    bucket_hist_kernel<<<512, 256, 0, stream>>>(dsts, bhist, E);
    bucket_scan_kernel<<<1, 256, 0, stream>>>(bhist, bbase, bcur);
    bin_kernel<<<(E + BIN_CH - 1) / BIN_CH, 256, 0, stream>>>(srcs, dsts, bcur, pairbuf, E);
    bucket_fill_kernel<<<NB, 256, 0, stream>>>(pairbuf, bbase, rowptr, col, N, E);

    const int gatherBlocks = (N + 3) / 4;
    // transform: 1 tile (16 nodes) per wave, 4 waves/block
    const int tiles    = (N + 15) / 16;
    const int xfBlocks = (tiles + 3) / 4;

    // ---- layer 0
    gather_mean_kernel<<<gatherBlocks, 256, 0, stream>>>(xb, rowptr, col, meanb, N);
    transform_mfma_kernel<<<xfBlocks, 256, 0, stream>>>(xb, meanb, Wl0, bl0, Wr0,
                                                        hA, nullptr, nullptr, N, 0);
    // ---- layer 1
    gather_mean_kernel<<<gatherBlocks, 256, 0, stream>>>(hA, rowptr, col, meanb, N);
    transform_mfma_kernel<<<xfBlocks, 256, 0, stream>>>(hA, meanb, Wl1, bl1, Wr1,
                                                        hB, nullptr, nullptr, N, 0);
    // ---- layer 2
    gather_mean_kernel<<<gatherBlocks, 256, 0, stream>>>(hB, rowptr, col, meanb, N);
    transform_mfma_kernel<<<xfBlocks, 256, 0, stream>>>(hB, meanb, Wl2, bl2, Wr2,
                                                        nullptr, batch, out, N, 1);
}

// Round 5
// 315.282 us; speedup vs baseline: 2.1545x; 1.0860x over previous
//
#include <hip/hip_runtime.h>

#define DFEAT 64

typedef __attribute__((ext_vector_type(8))) short bf16x8;   // 8 bf16 = 4 VGPRs
typedef __attribute__((ext_vector_type(4))) float f32x4;

// ---------------- bf16 helpers (OCP bfloat16, RNE pack) ----------------
__device__ __forceinline__ float bfhi(unsigned int u) {   // high 16 bits as bf16
    return __builtin_bit_cast(float, u & 0xFFFF0000u);
}
__device__ __forceinline__ float bflo(unsigned int u) {   // low 16 bits as bf16
    return __builtin_bit_cast(float, u << 16);
}
__device__ __forceinline__ unsigned short f2bf(float f) { // RNE
    unsigned int u = __builtin_bit_cast(unsigned int, f);
    u += 0x7FFFu + ((u >> 16) & 1u);
    return (unsigned short)(u >> 16);
}

// ============================================================================
// fp32 -> bf16 conversion of the input features (once per call)
// ============================================================================
__global__ void __launch_bounds__(256)
cvt_bf16_kernel(const float* __restrict__ in, unsigned short* __restrict__ outb,
                int n4) {   // n4 = total elements / 4
    int i = blockIdx.x * 256 + threadIdx.x;
    if (i >= n4) return;
    const float4 v = reinterpret_cast<const float4*>(in)[i];
    uint2 p;
    p.x = (unsigned int)f2bf(v.x) | ((unsigned int)f2bf(v.y) << 16);
    p.y = (unsigned int)f2bf(v.z) | ((unsigned int)f2bf(v.w) << 16);
    reinterpret_cast<uint2*>(outb)[i] = p;
}

// ============================================================================
// CSR build, binned two-pass.
// Bucket b = 256 consecutive dst nodes. NB = ceil(N/256) <= 512 (N=100000).
// Edges pack into u32: (dst & 255) << 24 | src   (needs src < 2^24).
// ============================================================================

__global__ void __launch_bounds__(256)
bucket_hist_kernel(const int* __restrict__ dsts, int* __restrict__ bhist, int E) {
    __shared__ int h[512];
    const int tid = threadIdx.x;
    h[tid] = 0; h[tid + 256] = 0;
    __syncthreads();
    for (int e = blockIdx.x * 256 + tid; e < E; e += gridDim.x * 256)
        atomicAdd(&h[dsts[e] >> 8], 1);
    __syncthreads();
    for (int b = tid; b < 512; b += 256)
        if (h[b]) atomicAdd(&bhist[b], h[b]);
}

__global__ void __launch_bounds__(256)
bucket_scan_kernel(const int* __restrict__ bhist, int* __restrict__ bbase,
                   int* __restrict__ bcur) {
    __shared__ int sm[512];
    const int tid = threadIdx.x;
    sm[tid] = bhist[tid]; sm[tid + 256] = bhist[tid + 256];
    __syncthreads();
    for (int s = 1; s < 512; s <<= 1) {
        int a0 = (tid >= s) ? sm[tid - s] : 0;
        int a1 = sm[tid + 256 - s];
        __syncthreads();
        sm[tid] += a0; sm[tid + 256] += a1;
        __syncthreads();
    }
    for (int b = tid; b < 512; b += 256) {
        int excl = b ? sm[b - 1] : 0;
        bbase[b] = excl; bcur[b] = excl;
    }
    if (tid == 0) bbase[512] = sm[511];
}

#define BIN_CH 2048
__global__ void __launch_bounds__(256)
bin_kernel(const int* __restrict__ srcs, const int* __restrict__ dsts,
           int* __restrict__ bcur, unsigned int* __restrict__ pairbuf, int E) {
    __shared__ int hist[512];
    __shared__ int sscan[512];
    __shared__ int gbase[512];
    __shared__ unsigned int staged[BIN_CH];
    __shared__ unsigned short sbkt[BIN_CH];

    const int tid = threadIdx.x;
    const int base = blockIdx.x * BIN_CH;
    const int chcnt = min(BIN_CH, E - base);

    hist[tid] = 0; hist[tid + 256] = 0;
    __syncthreads();

    unsigned int pk[8];
    unsigned short bb[8], rr[8];
#pragma unroll
    for (int k = 0; k < 8; ++k) {
        int i = k * 256 + tid;
        if (i < chcnt) {
            int e = base + i;
            int d = dsts[e];
            int s = srcs[e];
            int b = d >> 8;
            int r = atomicAdd(&hist[b], 1);
            pk[k] = ((unsigned int)(d & 255) << 24) | (unsigned int)s;
            bb[k] = (unsigned short)b;
            rr[k] = (unsigned short)r;
        } else {
            bb[k] = 0xFFFFu;
        }
    }
    __syncthreads();

    sscan[tid] = hist[tid]; sscan[tid + 256] = hist[tid + 256];
    __syncthreads();
    for (int s = 1; s < 512; s <<= 1) {
        int a0 = (tid >= s) ? sscan[tid - s] : 0;
        int a1 = sscan[tid + 256 - s];
        __syncthreads();
        sscan[tid] += a0; sscan[tid + 256] += a1;
        __syncthreads();
    }

    for (int b = tid; b < 512; b += 256) {
        int c = hist[b];
        gbase[b] = c ? atomicAdd(&bcur[b], c) : 0;
    }
    __syncthreads();

#pragma unroll
    for (int k = 0; k < 8; ++k) {
        if (bb[k] != 0xFFFFu) {
            int b = bb[k];
            int lpos = (b ? sscan[b - 1] : 0) + rr[k];
            staged[lpos] = pk[k];
            sbkt[lpos] = (unsigned short)b;
        }
    }
    __syncthreads();

    for (int i = tid; i < chcnt; i += 256) {
        int b = sbkt[i];
        int excl = b ? sscan[b - 1] : 0;
        pairbuf[gbase[b] + (i - excl)] = staged[i];
    }
}

__global__ void __launch_bounds__(256)
bucket_fill_kernel(const unsigned int* __restrict__ pairbuf,
                   const int* __restrict__ bbase,
                   int* __restrict__ rowptr, int* __restrict__ col,
                   int N, int E) {
    __shared__ int hist[256];
    __shared__ int scan_[256];
    __shared__ int cur[256];

    const int tid = threadIdx.x;
    const int b = blockIdx.x;
    const int node0 = b << 8;
    const int bb0 = bbase[b];
    const int cnt = bbase[b + 1] - bb0;

    hist[tid] = 0;
    __syncthreads();
    for (int i = tid; i < cnt; i += 256)
        atomicAdd(&hist[pairbuf[bb0 + i] >> 24], 1);
    __syncthreads();

    scan_[tid] = hist[tid];
    __syncthreads();
    for (int s = 1; s < 256; s <<= 1) {
        int a = (tid >= s) ? scan_[tid - s] : 0;
        __syncthreads();
        scan_[tid] += a;
        __syncthreads();
    }
    int excl = tid ? scan_[tid - 1] : 0;
    if (node0 + tid < N) rowptr[node0 + tid] = bb0 + excl;
    if (b == 0 && tid == 0) rowptr[N] = E;
    cur[tid] = bb0 + excl;
    __syncthreads();

    for (int i = tid; i < cnt; i += 256) {
        unsigned int p = pairbuf[bb0 + i];
        int pos = atomicAdd(&cur[p >> 24], 1);
        col[pos] = (int)(p & 0xFFFFFFu);
    }
}

// ============================================================================
// FUSED SAGE layer: per-lane fp32 neighbor-mean accumulation directly in
// MFMA B-fragment layout, then D = [Wl|Wr] @ [mean|x]^T (+bias, L2, relu).
//
// Tile = 16 nodes, one wave per tile. lane = 16q + c:
//   c = lane&15 -> node (B col / C col), q = lane>>4 -> k-octet.
// B-frag layout: lane (q,c) supplies mean elems [8q,8q+8) (F0) and
// [32+8q,32+8q+8) (F1) of node base+c -> each lane fp32-accumulates exactly
// its two 16B chunks of its node's neighbor rows. No shuffles, no
// cross-lane reduce, no mean buffer. Neighbor loop is per-lane (deg
// divergent, exec-masked), 2-deep software pipeline: col[j+2] + rows[j+1]
// in flight while accumulating rows[j]; clamped tail prefetches are
// cache-hit dups that are never accumulated.
// For fixed c, the 4 q-lanes' two uint4 loads tile the 128B row exactly.
//
// MFMA + epilogue identical to the verified round-4 kernel:
//   C/D col=lane&15=node, row=(lane>>4)*4+reg = feature -> lane (q,c) holds
//   node base+c, features 16n+4q+{0..3}; coalesced uint2 stores; L2-norm
//   reduce = 2 shfl_xor (16,32). Final layer: sorted batch -> tile almost
//   always graph-uniform -> wave-reduce, 16 atomics/wave.
// ============================================================================
__global__ void __launch_bounds__(256, 4)
fused_sage_kernel(const unsigned short* __restrict__ xb,
                  const int* __restrict__ rowptr, const int* __restrict__ col,
                  const float* __restrict__ Wl, const float* __restrict__ bl,
                  const float* __restrict__ Wr,
                  unsigned short* __restrict__ h_out,
                  const int* __restrict__ batch, float* __restrict__ out,
                  int n_nodes, int final_layer) {
    __shared__ __align__(16) unsigned short Wlds[8192];   // 16 frags * 512 ushort

    const int tid = threadIdx.x;

    // ---- stage [Wl|Wr] -> bf16 A-fragments in LDS (once per block) ----
    // element (feat,k) of Wsrc -> frag f=(feat>>4)*4 + isWr*2 + (k>>5),
    // lane = ((k>>3)&3)*16 + (feat&15), elem j = k&7.
    for (int i4 = tid; i4 < 1024; i4 += 256) {
        const float4 wl = reinterpret_cast<const float4*>(Wl)[i4];
        const float4 wr = reinterpret_cast<const float4*>(Wr)[i4];
        const int feat = i4 >> 4;
        const int n = feat >> 4, cc = feat & 15;
        const int k0 = (i4 & 15) << 2;           // 4 consecutive k, same octet half
        const int qq = (k0 >> 3) & 3, tl = k0 >> 5, j0 = k0 & 7;
        const int lofs = (qq * 16 + cc) * 8 + j0;
        unsigned short* d0 = &Wlds[(n * 4 + tl) * 512 + lofs];
        d0[0] = f2bf(wl.x); d0[1] = f2bf(wl.y); d0[2] = f2bf(wl.z); d0[3] = f2bf(wl.w);
        unsigned short* d1 = &Wlds[(n * 4 + 2 + tl) * 512 + lofs];
        d1[0] = f2bf(wr.x); d1[1] = f2bf(wr.y); d1[2] = f2bf(wr.z); d1[3] = f2bf(wr.w);
    }
    __syncthreads();

    const int tiles = (n_nodes + 15) >> 4;
    const int tile = blockIdx.x * 4 + (tid >> 6);
    if (tile >= tiles) return;               // after the only barrier: safe

    const int lane = tid & 63;
    const int c = lane & 15;     // node within tile
    const int q = lane >> 4;     // k-octet / feature quarter
    const bf16x8* fragp = reinterpret_cast<const bf16x8*>(Wlds);  // [f*64 + lane]

    const int base = tile << 4;
    const bool valid = (base + c) < n_nodes;
    const int node = valid ? (base + c) : (n_nodes - 1);

    // ---- fused gather: fp32 mean accumulation in fragment layout ----
    const uint4* rows4 = reinterpret_cast<const uint4*>(xb);   // 8 uint4 per row
    const int st = rowptr[node];
    const int deg = valid ? (rowptr[node + 1] - st) : 0;

    float accA[8], accB[8];
#pragma unroll
    for (int j = 0; j < 8; ++j) { accA[j] = 0.f; accB[j] = 0.f; }

    if (deg > 0) {
        int nbB = col[st];                                   // idx for j=0
        uint4 a0 = rows4[(size_t)nbB * 8 + q];               // rows j=0
        uint4 b0 = rows4[(size_t)nbB * 8 + 4 + q];
        nbB = col[st + min(1, deg - 1)];                     // idx for j=1 (clamped)
        for (int j = 0; j < deg; ++j) {
            const int nbC = col[st + min(j + 2, deg - 1)];   // prefetch col j+2
            const uint4 a1 = rows4[(size_t)nbB * 8 + q];     // rows j+1 (clamped dup at tail)
            const uint4 b1 = rows4[(size_t)nbB * 8 + 4 + q];
            // accumulate stage j (always a real neighbor)
            accA[0] += bflo(a0.x); accA[1] += bfhi(a0.x);
            accA[2] += bflo(a0.y); accA[3] += bfhi(a0.y);
            accA[4] += bflo(a0.z); accA[5] += bfhi(a0.z);
            accA[6] += bflo(a0.w); accA[7] += bfhi(a0.w);
            accB[0] += bflo(b0.x); accB[1] += bfhi(b0.x);
            accB[2] += bflo(b0.y); accB[3] += bfhi(b0.y);
            accB[4] += bflo(b0.z); accB[5] += bfhi(b0.z);
            accB[6] += bflo(b0.w); accB[7] += bfhi(b0.w);
            a0 = a1; b0 = b1; nbB = nbC;
        }
    }

    const float inv = (deg > 0) ? (1.0f / (float)deg) : 0.0f;
    bf16x8 F0, F1;
#pragma unroll
    for (int j = 0; j < 8; ++j) {
        F0[j] = (short)f2bf(accA[j] * inv);
        F1[j] = (short)f2bf(accB[j] * inv);
    }
    // x (root) fragments: same chunk addresses on this node's own row
    const uint4* xrow = reinterpret_cast<const uint4*>(&xb[(size_t)node * 64]);
    const bf16x8 F2 = __builtin_bit_cast(bf16x8, xrow[q]);        // k 64..95
    const bf16x8 F3 = __builtin_bit_cast(bf16x8, xrow[4 + q]);    // k 96..127

    // ---- MFMA: D = [Wl|Wr] @ [mean|x]^T ----
    f32x4 acc[4];
#pragma unroll
    for (int n = 0; n < 4; ++n) acc[n] = (f32x4){0.f, 0.f, 0.f, 0.f};

#pragma unroll
    for (int n = 0; n < 4; ++n) {
        bf16x8 w0 = fragp[(n * 4 + 0) * 64 + lane];   // Wl, k 0..31
        bf16x8 w1 = fragp[(n * 4 + 1) * 64 + lane];   // Wl, k 32..63
        bf16x8 w2 = fragp[(n * 4 + 2) * 64 + lane];   // Wr, k 0..31
        bf16x8 w3 = fragp[(n * 4 + 3) * 64 + lane];   // Wr, k 32..63
        acc[n] = __builtin_amdgcn_mfma_f32_16x16x32_bf16(w0, F0, acc[n], 0, 0, 0);
        acc[n] = __builtin_amdgcn_mfma_f32_16x16x32_bf16(w1, F1, acc[n], 0, 0, 0);
        acc[n] = __builtin_amdgcn_mfma_f32_16x16x32_bf16(w2, F2, acc[n], 0, 0, 0);
        acc[n] = __builtin_amdgcn_mfma_f32_16x16x32_bf16(w3, F3, acc[n], 0, 0, 0);
    }

    // ---- epilogue: bias, L2 norm over features (this lane's node), relu ----
    float v[4][4];
    float ss = 0.f;
#pragma unroll
    for (int n = 0; n < 4; ++n) {
        const float4 b4 = reinterpret_cast<const float4*>(bl)[n * 4 + q]; // feats 16n+4q+..
        v[n][0] = acc[n][0] + b4.x;
        v[n][1] = acc[n][1] + b4.y;
        v[n][2] = acc[n][2] + b4.z;
        v[n][3] = acc[n][3] + b4.w;
#pragma unroll
        for (int r = 0; r < 4; ++r) ss += v[n][r] * v[n][r];
    }
    ss += __shfl_xor(ss, 16, 64);
    ss += __shfl_xor(ss, 32, 64);
    const float nrm = 1.0f / fmaxf(sqrtf(ss), 1e-12f);

    if (!final_layer) {
        if (valid) {
            uint2* dst = reinterpret_cast<uint2*>(&h_out[(size_t)(base + c) * 64]);
#pragma unroll
            for (int n = 0; n < 4; ++n) {
                float o0 = fmaxf(v[n][0] * nrm, 0.f), o1 = fmaxf(v[n][1] * nrm, 0.f);
                float o2 = fmaxf(v[n][2] * nrm, 0.f), o3 = fmaxf(v[n][3] * nrm, 0.f);
                uint2 p;
                p.x = (unsigned int)f2bf(o0) | ((unsigned int)f2bf(o1) << 16);
                p.y = (unsigned int)f2bf(o2) | ((unsigned int)f2bf(o3) << 16);
                dst[n * 4 + q] = p;       // ushorts (base+c)*64 + 16n + 4q ..
            }
        }
    } else {
        float o[4][4];
#pragma unroll
        for (int n = 0; n < 4; ++n)
#pragma unroll
            for (int r = 0; r < 4; ++r)
                o[n][r] = valid ? fmaxf(v[n][r] * nrm, 0.f) : 0.f;

        const int lastn = min(base + 15, n_nodes - 1);
        const int gb0 = batch[base];
        if (gb0 == batch[lastn]) {
            // graph-uniform tile: reduce over the 16 nodes, 1 atomic per feat
#pragma unroll
            for (int n = 0; n < 4; ++n)
#pragma unroll
                for (int r = 0; r < 4; ++r) {
                    float s = o[n][r];
                    s += __shfl_xor(s, 1, 64);
                    s += __shfl_xor(s, 2, 64);
                    s += __shfl_xor(s, 4, 64);
                    s += __shfl_xor(s, 8, 64);
                    if (c == 0)
                        atomicAdd(&out[(size_t)gb0 * DFEAT + n * 16 + q * 4 + r], s);
                }
        } else {
            if (valid) {
                const int gb = batch[base + c];
#pragma unroll
                for (int n = 0; n < 4; ++n)
#pragma unroll
                    for (int r = 0; r < 4; ++r)
                        atomicAdd(&out[(size_t)gb * DFEAT + n * 16 + q * 4 + r], o[n][r]);
            }
        }
    }
}

// ============================================================================
extern "C" void kernel_launch(void* const* d_in, const int* in_sizes, int n_in,
                              void* d_out, int out_size, void* d_ws, size_t ws_size,
                              hipStream_t stream) {
    const float* x_raw = (const float*)d_in[0];
    const int*   eidx  = (const int*)d_in[1];
    const int*   batch = (const int*)d_in[2];
    const float* Wl0 = (const float*)d_in[3];
    const float* bl0 = (const float*)d_in[4];
    const float* Wr0 = (const float*)d_in[5];
    const float* Wl1 = (const float*)d_in[6];
    const float* bl1 = (const float*)d_in[7];
    const float* Wr1 = (const float*)d_in[8];
    const float* Wl2 = (const float*)d_in[9];
    const float* bl2 = (const float*)d_in[10];
    const float* Wr2 = (const float*)d_in[11];

    const int N = in_sizes[0] / DFEAT;
    const int E = in_sizes[1] / 2;
    const int* srcs = eidx;
    const int* dsts = eidx + E;
    float* out = (float*)d_out;

    const int NB = (N + 255) >> 8;   // buckets of 256 nodes; N=100000 -> 391 (<=512)

    char* ws = (char*)d_ws;
    auto align512 = [](size_t v) { return (v + 511) & ~(size_t)511; };
    size_t off = 0;
    int* rowptr = (int*)(ws + off); off += align512(((size_t)N + 1) * 4);
    int* col    = (int*)(ws + off); off += align512((size_t)E * 4);
    int* bhist  = (int*)(ws + off); off += align512(512 * 4);
    int* bbase  = (int*)(ws + off); off += align512(513 * 4);
    int* bcur   = (int*)(ws + off); off += align512(512 * 4);
    unsigned short* xb = (unsigned short*)(ws + off); off += align512((size_t)N * DFEAT * 2);
    unsigned short* hA = (unsigned short*)(ws + off); off += align512((size_t)N * DFEAT * 2);
    unsigned short* hB = (unsigned short*)(ws + off);
    // pairbuf only lives during CSR build, which completes before hA is first
    // written (layer-0 fused kernel) -> alias it onto hA. E*4 (6.4MB) <= N*128B.
    unsigned int* pairbuf = (unsigned int*)hA;

    hipMemsetAsync(bhist, 0, 512 * 4, stream);
    hipMemsetAsync(out, 0, (size_t)out_size * 4, stream);

    // input fp32 -> bf16 (once)
    const int n4 = N * DFEAT / 4;
    cvt_bf16_kernel<<<(n4 + 255) / 256, 256, 0, stream>>>(x_raw, xb, n4);

    // CSR build, binned two-pass (once)
    bucket_hist_kernel<<<512, 256, 0, stream>>>(dsts, bhist, E);
    bucket_scan_kernel<<<1, 256, 0, stream>>>(bhist, bbase, bcur);
    bin_kernel<<<(E + BIN_CH - 1) / BIN_CH, 256, 0, stream>>>(srcs, dsts, bcur, pairbuf, E);
    bucket_fill_kernel<<<NB, 256, 0, stream>>>(pairbuf, bbase, rowptr, col, N, E);

    // fused layers: 1 tile (16 nodes) per wave, 4 waves/block
    const int tiles    = (N + 15) / 16;
    const int xfBlocks = (tiles + 3) / 4;

    fused_sage_kernel<<<xfBlocks, 256, 0, stream>>>(xb, rowptr, col, Wl0, bl0, Wr0,
                                                    hA, nullptr, nullptr, N, 0);
    fused_sage_kernel<<<xfBlocks, 256, 0, stream>>>(hA, rowptr, col, Wl1, bl1, Wr1,
                                                    hB, nullptr, nullptr, N, 0);
    fused_sage_kernel<<<xfBlocks, 256, 0, stream>>>(hB, rowptr, col, Wl2, bl2, Wr2,
                                                    nullptr, batch, out, N, 1);
}